// Round 1
// baseline (667.835 us; speedup 1.0000x reference)
//
#include <hip/hip_runtime.h>
#include <hip/hip_bf16.h>
#include <math.h>

#define IN_C 128
#define HC   256
#define CH   64
#define NEG  0.2f

// order-preserving float<->uint encoding for atomicMax on floats
__device__ __forceinline__ unsigned enc_f(float f) {
    unsigned u = __float_as_uint(f);
    return (u & 0x80000000u) ? ~u : (u | 0x80000000u);
}
__device__ __forceinline__ float dec_f(unsigned u) {
    return __uint_as_float((u & 0x80000000u) ? (u & 0x7FFFFFFFu) : ~u);
}
__device__ __forceinline__ float lrelu(float v) { return v > 0.f ? v : NEG * v; }

// ---------------- GEMM: xl = x @ W^T, fused a_src/a_dst epilogue ----------------
// block = 256 threads, tile = 64 nodes x 256 outs, K chunked by 32.
// thread micro-tile: 8 nodes x 8 outs.  r = t>>5 (node group), c = t&31 (out group).
__global__ void k_gemm(const float* __restrict__ x, const float* __restrict__ W,
                       const float* __restrict__ att_src, const float* __restrict__ att_dst,
                       float* __restrict__ xl, float* __restrict__ asrc, float* __restrict__ adst,
                       int N)
{
    __shared__ float xs[32][68];    // [k][node], padded
    __shared__ float wsh[32][260];  // [k][out], padded

    const int t  = threadIdx.x;
    const int n0 = blockIdx.x * 64;
    const int r  = t >> 5;
    const int c  = t & 31;

    float acc[8][8];
#pragma unroll
    for (int i = 0; i < 8; ++i)
#pragma unroll
        for (int j = 0; j < 8; ++j) acc[i][j] = 0.f;

    for (int kc = 0; kc < IN_C; kc += 32) {
        __syncthreads();
        // stage x tile: 64 nodes x 32 k
#pragma unroll
        for (int i = 0; i < 2; ++i) {
            int L = t + 256 * i;
            int node = L >> 3, q = L & 7;
            int row = n0 + node; if (row > N - 1) row = N - 1;
            const float4 v = *(const float4*)&x[row * IN_C + kc + q * 4];
            xs[q * 4 + 0][node] = v.x; xs[q * 4 + 1][node] = v.y;
            xs[q * 4 + 2][node] = v.z; xs[q * 4 + 3][node] = v.w;
        }
        // stage W tile: 256 outs x 32 k
#pragma unroll
        for (int i = 0; i < 8; ++i) {
            int L = t + 256 * i;
            int out = L >> 3, q = L & 7;
            const float4 v = *(const float4*)&W[out * IN_C + kc + q * 4];
            wsh[q * 4 + 0][out] = v.x; wsh[q * 4 + 1][out] = v.y;
            wsh[q * 4 + 2][out] = v.z; wsh[q * 4 + 3][out] = v.w;
        }
        __syncthreads();
#pragma unroll 8
        for (int k = 0; k < 32; ++k) {
            const float4 xa = *(const float4*)&xs[k][r * 8];
            const float4 xb = *(const float4*)&xs[k][r * 8 + 4];
            const float4 wa = *(const float4*)&wsh[k][c * 8];
            const float4 wb = *(const float4*)&wsh[k][c * 8 + 4];
            const float xr[8] = {xa.x, xa.y, xa.z, xa.w, xb.x, xb.y, xb.z, xb.w};
            const float wr[8] = {wa.x, wa.y, wa.z, wa.w, wb.x, wb.y, wb.z, wb.w};
#pragma unroll
            for (int i = 0; i < 8; ++i)
#pragma unroll
                for (int j = 0; j < 8; ++j)
                    acc[i][j] = fmaf(xr[i], wr[j], acc[i][j]);
        }
    }

    // epilogue: store xl + fused attention logits
    const int head = c >> 3;
    const int sub  = c & 7;
    const float4 sa = *(const float4*)&att_src[head * CH + sub * 8];
    const float4 sb = *(const float4*)&att_src[head * CH + sub * 8 + 4];
    const float4 da = *(const float4*)&att_dst[head * CH + sub * 8];
    const float4 db = *(const float4*)&att_dst[head * CH + sub * 8 + 4];
    const float as8[8] = {sa.x, sa.y, sa.z, sa.w, sb.x, sb.y, sb.z, sb.w};
    const float ad8[8] = {da.x, da.y, da.z, da.w, db.x, db.y, db.z, db.w};

#pragma unroll
    for (int i = 0; i < 8; ++i) {
        int row = n0 + r * 8 + i;
        float ps = 0.f, pd = 0.f;
#pragma unroll
        for (int j = 0; j < 8; ++j) {
            ps = fmaf(acc[i][j], as8[j], ps);
            pd = fmaf(acc[i][j], ad8[j], pd);
        }
#pragma unroll
        for (int m = 1; m < 8; m <<= 1) {
            ps += __shfl_xor(ps, m);
            pd += __shfl_xor(pd, m);
        }
        if (row < N) {
            *(float4*)&xl[row * HC + c * 8]     = make_float4(acc[i][0], acc[i][1], acc[i][2], acc[i][3]);
            *(float4*)&xl[row * HC + c * 8 + 4] = make_float4(acc[i][4], acc[i][5], acc[i][6], acc[i][7]);
            if (sub == 0) {
                asrc[row * 4 + head] = ps;
                adst[row * 4 + head] = pd;
            }
        }
    }
}

// ---------------- per-edge scores: segment max + degree histogram ----------------
__global__ void k_scores(const int* __restrict__ ei, const float* __restrict__ asrc,
                         const float* __restrict__ adst, unsigned* __restrict__ amax,
                         int* __restrict__ deg, int N, int E)
{
    int e = blockIdx.x * 256 + threadIdx.x;
    int tot = E + N;
    if (e >= tot) return;
    int s, d;
    if (e < E) { s = ei[e]; d = ei[E + e]; } else { s = d = e - E; }
#pragma unroll
    for (int h = 0; h < 4; ++h) {
        float al = lrelu(asrc[s * 4 + h] + adst[d * 4 + h]);
        atomicMax(&amax[d * 4 + h], enc_f(al));
    }
    if (e < E) atomicAdd(&deg[d], 1);
}

// ---------------- exclusive scan (2-level) ----------------
__global__ void k_scan1(const int* __restrict__ deg, int* __restrict__ offs,
                        int* __restrict__ partials, int N)
{
    __shared__ int sh[1024];
    int t = threadIdx.x, b = blockIdx.x;
    int idx = b * 1024 + t;
    int v = (idx < N) ? deg[idx] : 0;
    sh[t] = v; __syncthreads();
    for (int off = 1; off < 1024; off <<= 1) {
        int u = (t >= off) ? sh[t - off] : 0;
        __syncthreads();
        sh[t] += u;
        __syncthreads();
    }
    if (idx < N) offs[idx] = sh[t] - v;
    if (t == 1023) partials[b] = sh[t];
}

__global__ void k_scan2(int* __restrict__ partials, int nparts)
{
    __shared__ int sh[1024];
    int t = threadIdx.x;
    int v = (t < nparts) ? partials[t] : 0;
    sh[t] = v; __syncthreads();
    for (int off = 1; off < 1024; off <<= 1) {
        int u = (t >= off) ? sh[t - off] : 0;
        __syncthreads();
        sh[t] += u;
        __syncthreads();
    }
    if (t < nparts) partials[t] = sh[t] - v;  // exclusive
}

__global__ void k_scan3(int* __restrict__ offs, int* __restrict__ cursor,
                        const int* __restrict__ partials, int N, int E)
{
    int t = threadIdx.x, b = blockIdx.x;
    int idx = b * 1024 + t;
    if (idx < N) {
        int v = offs[idx] + partials[b];
        offs[idx] = v;
        cursor[idx] = v;
    }
    if (idx == 0) offs[N] = E;
}

// ---------------- scatter to CSR + softmax denominator ----------------
__global__ void k_scatter(const int* __restrict__ ei, const float* __restrict__ asrc,
                          const float* __restrict__ adst, const unsigned* __restrict__ amax,
                          float* __restrict__ denom, int* __restrict__ cursor,
                          int* __restrict__ csr_src, int N, int E)
{
    int e = blockIdx.x * 256 + threadIdx.x;
    int tot = E + N;
    if (e >= tot) return;
    int s, d;
    if (e < E) {
        s = ei[e]; d = ei[E + e];
        int pos = atomicAdd(&cursor[d], 1);
        csr_src[pos] = s;
    } else {
        s = d = e - E;
    }
#pragma unroll
    for (int h = 0; h < 4; ++h) {
        float al = lrelu(asrc[s * 4 + h] + adst[d * 4 + h]);
        float ex = __expf(al - dec_f(amax[d * 4 + h]));
        atomicAdd(&denom[d * 4 + h], ex);
    }
}

// ---------------- gather-aggregate: block per node, wave per head, lane per channel ----------------
__global__ void __launch_bounds__(256) k_agg(
    const float* __restrict__ xl, const float* __restrict__ asrc,
    const float* __restrict__ adst, const unsigned* __restrict__ amax,
    const float* __restrict__ denom, const int* __restrict__ offs,
    const int* __restrict__ csr_src, const float* __restrict__ bias,
    float* __restrict__ out, int N)
{
    const int n = blockIdx.x;
    const int t = threadIdx.x;
    const int h = t >> 6;
    const int c = t & 63;
    const int off = h * CH + c;

    const float adn = adst[n * 4 + h];
    const float mx  = dec_f(amax[n * 4 + h]);
    const float inv = 1.0f / denom[n * 4 + h];

    // self loop
    float als = lrelu(asrc[n * 4 + h] + adn);
    float acc = __expf(als - mx) * xl[n * HC + off];

    int p  = offs[n];
    int pe = offs[n + 1];
    for (; p + 4 <= pe; p += 4) {
        int s0 = csr_src[p], s1 = csr_src[p + 1], s2 = csr_src[p + 2], s3 = csr_src[p + 3];
        float a0 = asrc[s0 * 4 + h], a1 = asrc[s1 * 4 + h];
        float a2 = asrc[s2 * 4 + h], a3 = asrc[s3 * 4 + h];
        float x0 = xl[s0 * HC + off], x1 = xl[s1 * HC + off];
        float x2 = xl[s2 * HC + off], x3 = xl[s3 * HC + off];
        float w0 = __expf(lrelu(a0 + adn) - mx);
        float w1 = __expf(lrelu(a1 + adn) - mx);
        float w2 = __expf(lrelu(a2 + adn) - mx);
        float w3 = __expf(lrelu(a3 + adn) - mx);
        acc = fmaf(w0, x0, acc);
        acc = fmaf(w1, x1, acc);
        acc = fmaf(w2, x2, acc);
        acc = fmaf(w3, x3, acc);
    }
    for (; p < pe; ++p) {
        int s = csr_src[p];
        float a = lrelu(asrc[s * 4 + h] + adn);
        acc = fmaf(__expf(a - mx), xl[s * HC + off], acc);
    }

    float v = fmaf(acc, inv, 0.f) + bias[off];
    out[n * HC + off] = v > 0.f ? v : expm1f(v);
}

extern "C" void kernel_launch(void* const* d_in, const int* in_sizes, int n_in,
                              void* d_out, int out_size, void* d_ws, size_t ws_size,
                              hipStream_t stream) {
    const float* x       = (const float*)d_in[0];
    const int*   ei      = (const int*)d_in[1];   // [2][E] int32
    const float* W       = (const float*)d_in[2];
    const float* att_src = (const float*)d_in[3];
    const float* att_dst = (const float*)d_in[4];
    const float* bias    = (const float*)d_in[5];
    float* out = (float*)d_out;

    const int N = in_sizes[0] / IN_C;
    const int E = in_sizes[1] / 2;

    char* p = (char*)d_ws;
    auto alloc = [&](size_t bytes) -> char* {
        char* q = p;
        p += (bytes + 255) & ~(size_t)255;
        return q;
    };
    float*    xl       = (float*)alloc((size_t)N * HC * 4);
    float*    asrc     = (float*)alloc((size_t)N * 4 * 4);
    float*    adst     = (float*)alloc((size_t)N * 4 * 4);
    unsigned* amax     = (unsigned*)alloc((size_t)N * 4 * 4);
    float*    denom    = (float*)alloc((size_t)N * 4 * 4);
    int*      deg      = (int*)alloc((size_t)N * 4);
    int*      offs     = (int*)alloc((size_t)(N + 1) * 4);
    int*      cursor   = (int*)alloc((size_t)N * 4);
    int*      partials = (int*)alloc(4096);
    int*      csr      = (int*)alloc((size_t)E * 4);

    hipMemsetAsync(amax, 0, (size_t)N * 4 * 4, stream);
    hipMemsetAsync(denom, 0, (size_t)N * 4 * 4, stream);
    hipMemsetAsync(deg, 0, (size_t)N * 4, stream);

    k_gemm<<<(N + 63) / 64, 256, 0, stream>>>(x, W, att_src, att_dst, xl, asrc, adst, N);

    const int tot = E + N;
    k_scores<<<(tot + 255) / 256, 256, 0, stream>>>(ei, asrc, adst, amax, deg, N, E);

    const int nb = (N + 1023) / 1024;
    k_scan1<<<nb, 1024, 0, stream>>>(deg, offs, partials, N);
    k_scan2<<<1, 1024, 0, stream>>>(partials, nb);
    k_scan3<<<nb, 1024, 0, stream>>>(offs, cursor, partials, N, E);

    k_scatter<<<(tot + 255) / 256, 256, 0, stream>>>(ei, asrc, adst, amax, denom, cursor, csr, N, E);

    k_agg<<<N, 256, 0, stream>>>(xl, asrc, adst, amax, denom, offs, csr, bias, out, N);
}

// Round 2
// 363.139 us; speedup vs baseline: 1.8391x; 1.8391x over previous
//
#include <hip/hip_runtime.h>
#include <hip/hip_bf16.h>
#include <math.h>

#define IN_C 128
#define HC   256
#define CH   64
#define NEG  0.2f

__device__ __forceinline__ float lrelu(float v) { return v > 0.f ? v : NEG * v; }

// ---------------- GEMM: xl = x @ W^T, fused a_src/a_dst epilogue ----------------
__global__ void k_gemm(const float* __restrict__ x, const float* __restrict__ W,
                       const float* __restrict__ att_src, const float* __restrict__ att_dst,
                       float* __restrict__ xl, float* __restrict__ asrc, float* __restrict__ adst,
                       int N)
{
    __shared__ float xs[32][68];    // [k][node], padded
    __shared__ float wsh[32][260];  // [k][out], padded

    const int t  = threadIdx.x;
    const int n0 = blockIdx.x * 64;
    const int r  = t >> 5;
    const int c  = t & 31;

    float acc[8][8];
#pragma unroll
    for (int i = 0; i < 8; ++i)
#pragma unroll
        for (int j = 0; j < 8; ++j) acc[i][j] = 0.f;

    for (int kc = 0; kc < IN_C; kc += 32) {
        __syncthreads();
#pragma unroll
        for (int i = 0; i < 2; ++i) {
            int L = t + 256 * i;
            int node = L >> 3, q = L & 7;
            int row = n0 + node; if (row > N - 1) row = N - 1;
            const float4 v = *(const float4*)&x[row * IN_C + kc + q * 4];
            xs[q * 4 + 0][node] = v.x; xs[q * 4 + 1][node] = v.y;
            xs[q * 4 + 2][node] = v.z; xs[q * 4 + 3][node] = v.w;
        }
#pragma unroll
        for (int i = 0; i < 8; ++i) {
            int L = t + 256 * i;
            int out = L >> 3, q = L & 7;
            const float4 v = *(const float4*)&W[out * IN_C + kc + q * 4];
            wsh[q * 4 + 0][out] = v.x; wsh[q * 4 + 1][out] = v.y;
            wsh[q * 4 + 2][out] = v.z; wsh[q * 4 + 3][out] = v.w;
        }
        __syncthreads();
#pragma unroll 8
        for (int k = 0; k < 32; ++k) {
            const float4 xa = *(const float4*)&xs[k][r * 8];
            const float4 xb = *(const float4*)&xs[k][r * 8 + 4];
            const float4 wa = *(const float4*)&wsh[k][c * 8];
            const float4 wb = *(const float4*)&wsh[k][c * 8 + 4];
            const float xr[8] = {xa.x, xa.y, xa.z, xa.w, xb.x, xb.y, xb.z, xb.w};
            const float wr[8] = {wa.x, wa.y, wa.z, wa.w, wb.x, wb.y, wb.z, wb.w};
#pragma unroll
            for (int i = 0; i < 8; ++i)
#pragma unroll
                for (int j = 0; j < 8; ++j)
                    acc[i][j] = fmaf(xr[i], wr[j], acc[i][j]);
        }
    }

    const int head = c >> 3;
    const int sub  = c & 7;
    const float4 sa = *(const float4*)&att_src[head * CH + sub * 8];
    const float4 sb = *(const float4*)&att_src[head * CH + sub * 8 + 4];
    const float4 da = *(const float4*)&att_dst[head * CH + sub * 8];
    const float4 db = *(const float4*)&att_dst[head * CH + sub * 8 + 4];
    const float as8[8] = {sa.x, sa.y, sa.z, sa.w, sb.x, sb.y, sb.z, sb.w};
    const float ad8[8] = {da.x, da.y, da.z, da.w, db.x, db.y, db.z, db.w};

#pragma unroll
    for (int i = 0; i < 8; ++i) {
        int row = n0 + r * 8 + i;
        float ps = 0.f, pd = 0.f;
#pragma unroll
        for (int j = 0; j < 8; ++j) {
            ps = fmaf(acc[i][j], as8[j], ps);
            pd = fmaf(acc[i][j], ad8[j], pd);
        }
#pragma unroll
        for (int m = 1; m < 8; m <<= 1) {
            ps += __shfl_xor(ps, m);
            pd += __shfl_xor(pd, m);
        }
        if (row < N) {
            *(float4*)&xl[row * HC + c * 8]     = make_float4(acc[i][0], acc[i][1], acc[i][2], acc[i][3]);
            *(float4*)&xl[row * HC + c * 8 + 4] = make_float4(acc[i][4], acc[i][5], acc[i][6], acc[i][7]);
            if (sub == 0) {
                asrc[row * 4 + head] = ps;
                adst[row * 4 + head] = pd;
            }
        }
    }
}

// ---------------- degree histogram; atomic return value = within-segment rank ----------------
__global__ void k_deg(const int* __restrict__ ei, int* __restrict__ deg,
                      int* __restrict__ perm, int E)
{
    int e = blockIdx.x * 256 + threadIdx.x;
    if (e >= E) return;
    int d = ei[E + e];
    perm[e] = atomicAdd(&deg[d], 1);
}

// ---------------- exclusive scan (2-level) ----------------
__global__ void k_scan1(const int* __restrict__ deg, int* __restrict__ offs,
                        int* __restrict__ partials, int N)
{
    __shared__ int sh[1024];
    int t = threadIdx.x, b = blockIdx.x;
    int idx = b * 1024 + t;
    int v = (idx < N) ? deg[idx] : 0;
    sh[t] = v; __syncthreads();
    for (int off = 1; off < 1024; off <<= 1) {
        int u = (t >= off) ? sh[t - off] : 0;
        __syncthreads();
        sh[t] += u;
        __syncthreads();
    }
    if (idx < N) offs[idx] = sh[t] - v;
    if (t == 1023) partials[b] = sh[t];
}

__global__ void k_scan2(int* __restrict__ partials, int nparts)
{
    __shared__ int sh[1024];
    int t = threadIdx.x;
    int v = (t < nparts) ? partials[t] : 0;
    sh[t] = v; __syncthreads();
    for (int off = 1; off < 1024; off <<= 1) {
        int u = (t >= off) ? sh[t - off] : 0;
        __syncthreads();
        sh[t] += u;
        __syncthreads();
    }
    if (t < nparts) partials[t] = sh[t] - v;  // exclusive
}

__global__ void k_scan3(int* __restrict__ offs, const int* __restrict__ partials,
                        int N, int E)
{
    int t = threadIdx.x, b = blockIdx.x;
    int idx = b * 1024 + t;
    if (idx < N) offs[idx] += partials[b];
    if (idx == 0) offs[N] = E;
}

// ---------------- atomic-free CSR placement ----------------
__global__ void k_place(const int* __restrict__ ei, const int* __restrict__ perm,
                        const int* __restrict__ offs, int* __restrict__ csr_src, int E)
{
    int e = blockIdx.x * 256 + threadIdx.x;
    if (e >= E) return;
    int s = ei[e];
    int d = ei[E + e];
    csr_src[offs[d] + perm[e]] = s;
}

// ---------------- gather-aggregate with fused online softmax ----------------
// block per node; wave per head; lane per channel. No atomics anywhere.
__global__ void __launch_bounds__(256) k_agg(
    const float* __restrict__ xl, const float* __restrict__ asrc,
    const float* __restrict__ adst, const int* __restrict__ offs,
    const int* __restrict__ csr_src, const float* __restrict__ bias,
    float* __restrict__ out, int N)
{
    const int n    = blockIdx.x;
    const int t    = threadIdx.x;
    const int h    = t >> 6;
    const int lane = t & 63;
    const int off  = h * CH + lane;

    const float adn    = adst[n * 4 + h];
    const float a_self = lrelu(asrc[n * 4 + h] + adn);
    const int   p0 = offs[n];
    const int   pe = offs[n + 1];

    // ---- pass A: online softmax stats (m, l) per head across incoming edges ----
    float m = -1e30f, l = 0.f;
    if (lane == 0) { m = a_self; l = 1.f; }   // self loop
    for (int p = p0 + lane; p < pe; p += 64) {
        int s = csr_src[p];
        float a = lrelu(asrc[s * 4 + h] + adn);
        if (a > m) { l = l * __expf(m - a) + 1.f; m = a; }
        else       { l += __expf(a - m); }
    }
#pragma unroll
    for (int mask = 1; mask < 64; mask <<= 1) {
        float om = __shfl_xor(m, mask);
        float ol = __shfl_xor(l, mask);
        float nm = fmaxf(m, om);
        l = l * __expf(m - nm) + ol * __expf(om - nm);
        m = nm;
    }
    const float inv = 1.0f / l;

    // ---- pass B: weighted gather of source features ----
    float acc = __expf(a_self - m) * xl[n * HC + off];
    int p = p0;
    for (; p + 4 <= pe; p += 4) {
        int s0 = csr_src[p], s1 = csr_src[p + 1], s2 = csr_src[p + 2], s3 = csr_src[p + 3];
        float a0 = asrc[s0 * 4 + h], a1 = asrc[s1 * 4 + h];
        float a2 = asrc[s2 * 4 + h], a3 = asrc[s3 * 4 + h];
        float x0 = xl[s0 * HC + off], x1 = xl[s1 * HC + off];
        float x2 = xl[s2 * HC + off], x3 = xl[s3 * HC + off];
        acc = fmaf(__expf(lrelu(a0 + adn) - m), x0, acc);
        acc = fmaf(__expf(lrelu(a1 + adn) - m), x1, acc);
        acc = fmaf(__expf(lrelu(a2 + adn) - m), x2, acc);
        acc = fmaf(__expf(lrelu(a3 + adn) - m), x3, acc);
    }
    for (; p < pe; ++p) {
        int s = csr_src[p];
        float a = lrelu(asrc[s * 4 + h] + adn);
        acc = fmaf(__expf(a - m), xl[s * HC + off], acc);
    }

    float v = acc * inv + bias[off];
    out[n * HC + off] = v > 0.f ? v : expm1f(v);
}

extern "C" void kernel_launch(void* const* d_in, const int* in_sizes, int n_in,
                              void* d_out, int out_size, void* d_ws, size_t ws_size,
                              hipStream_t stream) {
    const float* x       = (const float*)d_in[0];
    const int*   ei      = (const int*)d_in[1];   // [2][E] int32
    const float* W       = (const float*)d_in[2];
    const float* att_src = (const float*)d_in[3];
    const float* att_dst = (const float*)d_in[4];
    const float* bias    = (const float*)d_in[5];
    float* out = (float*)d_out;

    const int N = in_sizes[0] / IN_C;
    const int E = in_sizes[1] / 2;

    char* p = (char*)d_ws;
    auto alloc = [&](size_t bytes) -> char* {
        char* q = p;
        p += (bytes + 255) & ~(size_t)255;
        return q;
    };
    float* xl       = (float*)alloc((size_t)N * HC * 4);
    float* asrc     = (float*)alloc((size_t)N * 4 * 4);
    float* adst     = (float*)alloc((size_t)N * 4 * 4);
    int*   deg      = (int*)alloc((size_t)N * 4);
    int*   offs     = (int*)alloc((size_t)(N + 1) * 4);
    int*   perm     = (int*)alloc((size_t)E * 4);
    int*   partials = (int*)alloc(4096);
    int*   csr      = (int*)alloc((size_t)E * 4);

    hipMemsetAsync(deg, 0, (size_t)N * 4, stream);

    k_gemm<<<(N + 63) / 64, 256, 0, stream>>>(x, W, att_src, att_dst, xl, asrc, adst, N);

    k_deg<<<(E + 255) / 256, 256, 0, stream>>>(ei, deg, perm, E);

    const int nb = (N + 1023) / 1024;
    k_scan1<<<nb, 1024, 0, stream>>>(deg, offs, partials, N);
    k_scan2<<<1, 1024, 0, stream>>>(partials, nb);
    k_scan3<<<nb, 1024, 0, stream>>>(offs, partials, N, E);

    k_place<<<(E + 255) / 256, 256, 0, stream>>>(ei, perm, offs, csr, E);

    k_agg<<<N, 256, 0, stream>>>(xl, asrc, adst, offs, csr, bias, out, N);
}